// Round 1
// baseline (12636.291 us; speedup 1.0000x reference)
//
#include <hip/hip_runtime.h>
#include <stdint.h>

#define B_  64
#define S_  512
#define E_  256
#define H_  512

typedef float  f32x4  __attribute__((ext_vector_type(4)));
typedef __bf16 bf16x8 __attribute__((ext_vector_type(8)));

__device__ __forceinline__ unsigned short f2b(float f) {
  uint32_t u = __builtin_bit_cast(uint32_t, f);
  uint32_t r = (u + 0x7FFFu + ((u >> 16) & 1u)) >> 16;
  return (unsigned short)r;
}
__device__ __forceinline__ float b2f(unsigned short s) {
  uint32_t u = ((uint32_t)s) << 16;
  return __builtin_bit_cast(float, u);
}
__device__ __forceinline__ bf16x8 ld_bf8(const unsigned short* p) {
  uint4 v = *reinterpret_cast<const uint4*>(p);
  return __builtin_bit_cast(bf16x8, v);
}

// ---------------- convert emb + W_ih to bf16 ----------------
__global__ void convert_kernel(const float* __restrict__ emb,
                               const float* __restrict__ wih,
                               unsigned short* __restrict__ emb_b,
                               unsigned short* __restrict__ wih_b) {
  const int64_t EMB_N = (int64_t)32000 * 256;          // 8,192,000
  const int64_t TOT8  = (EMB_N + (int64_t)1536 * 256) / 8;
  for (int64_t i8 = (int64_t)blockIdx.x * blockDim.x + threadIdx.x; i8 < TOT8;
       i8 += (int64_t)gridDim.x * blockDim.x) {
    int64_t e = i8 * 8;
    const float* src; unsigned short* dst;
    if (e < EMB_N) { src = emb + e;           dst = emb_b + e; }
    else           { src = wih + (e - EMB_N); dst = wih_b + (e - EMB_N); }
    float4 a = *reinterpret_cast<const float4*>(src);
    float4 b = *reinterpret_cast<const float4*>(src + 4);
    uint4 o;
    o.x = (unsigned)f2b(a.x) | ((unsigned)f2b(a.y) << 16);
    o.y = (unsigned)f2b(a.z) | ((unsigned)f2b(a.w) << 16);
    o.z = (unsigned)f2b(b.x) | ((unsigned)f2b(b.y) << 16);
    o.w = (unsigned)f2b(b.z) | ((unsigned)f2b(b.w) << 16);
    *reinterpret_cast<uint4*>(dst) = o;
  }
}

// ---------------- sequence lengths ----------------
__global__ void lengths_kernel(const int* __restrict__ x, int* __restrict__ len) {
  __shared__ int part[8];
  int b = blockIdx.x, tid = threadIdx.x;
  int v = (x[b * S_ + tid] != 0) ? 1 : 0;
  unsigned long long m = __ballot(v);
  if ((tid & 63) == 0) part[tid >> 6] = __popcll(m);
  __syncthreads();
  if (tid == 0) {
    int s = 0;
    #pragma unroll
    for (int i = 0; i < 8; ++i) s += part[i];
    len[b] = s;
  }
}

// ---------------- phase 1: gi = emb[x] @ W_ih^T + b_ih  (permuted bf16 layout) ----
// gi_perm[t][wg=g*16+w][i(16)][c(96)]  where c = part*32 + c_hidden, gate row =
// part*512 + w*32 + c_hidden
__global__ __launch_bounds__(256) void gi_kernel(
    const int* __restrict__ x, const unsigned short* __restrict__ emb_b,
    const unsigned short* __restrict__ wih_b, const float* __restrict__ b_ih,
    unsigned short* __restrict__ gi) {
  int tblk = blockIdx.x, g = blockIdx.y, w = blockIdx.z;
  int tid = threadIdx.x;
  int wv = tid >> 6, lane = tid & 63;
  int c16 = lane & 15, kq = lane >> 4;
  int t0 = tblk * 8 + wv, t1 = t0 + 4;

  int grow[6]; float bias[6];
  #pragma unroll
  for (int nt = 0; nt < 6; ++nt) {
    grow[nt] = (nt >> 1) * H_ + w * 32 + (nt & 1) * 16 + c16;
    bias[nt] = b_ih[grow[nt]];
  }
  int tok0 = x[(g * 16 + c16) * S_ + t0];
  int tok1 = x[(g * 16 + c16) * S_ + t1];

  f32x4 acc[2][6];
  #pragma unroll
  for (int nt = 0; nt < 6; ++nt) {
    acc[0][nt] = f32x4{bias[nt], bias[nt], bias[nt], bias[nt]};
    acc[1][nt] = acc[0][nt];
  }
  #pragma unroll
  for (int kk = 0; kk < 8; ++kk) {
    int kb = kk * 32 + kq * 8;
    bf16x8 A0 = ld_bf8(emb_b + (size_t)tok0 * E_ + kb);
    bf16x8 A1 = ld_bf8(emb_b + (size_t)tok1 * E_ + kb);
    #pragma unroll
    for (int nt = 0; nt < 6; ++nt) {
      bf16x8 Bf = ld_bf8(wih_b + (size_t)grow[nt] * E_ + kb);
      acc[0][nt] = __builtin_amdgcn_mfma_f32_16x16x32_bf16(A0, Bf, acc[0][nt], 0, 0, 0);
      acc[1][nt] = __builtin_amdgcn_mfma_f32_16x16x32_bf16(A1, Bf, acc[1][nt], 0, 0, 0);
    }
  }
  int wg = g * 16 + w;
  #pragma unroll
  for (int m = 0; m < 2; ++m) {
    int t = m ? t1 : t0;
    size_t base = ((size_t)(t * 64 + wg) * 16) * 96;
    #pragma unroll
    for (int nt = 0; nt < 6; ++nt)
      #pragma unroll
      for (int j = 0; j < 4; ++j)
        gi[base + (size_t)(kq * 4 + j) * 96 + nt * 16 + c16] = f2b(acc[m][nt][j]);
  }
}

// ---------------- phase 2: persistent GRU scan ----------------
// 64 WGs = 4 batch-groups x 16 H-slice WGs. W_hh slice lives in registers.
// Per-step: MFMA [16,96,512] -> gates -> h_new slice -> global all-gather +
// per-cluster flag barrier (device scope).
__global__ __launch_bounds__(768, 1) void scan_kernel(
    const float* __restrict__ whh, const float* __restrict__ b_hh,
    const unsigned short* __restrict__ gi, const int* __restrict__ len,
    unsigned short* __restrict__ xchg, int* __restrict__ flags,
    float* __restrict__ out) {
  __shared__ float gh[2][16 * 100];   // two K-halves, padded stride 100
  __shared__ float hown[16 * 32];     // own f32 slice of h

  const int wgid = blockIdx.x, g = wgid >> 4, w = wgid & 15;
  const int tid = threadIdx.x, wv = tid >> 6, lane = tid & 63;
  const int nt = wv % 6, kh = wv / 6;           // 12 waves: 6 n-tiles x 2 K-halves
  const int c16 = lane & 15, kq = lane >> 4;

  // loop-invariant W_hh B-fragments in registers (bf16)
  const int grow = (nt >> 1) * H_ + w * 32 + (nt & 1) * 16 + c16;
  bf16x8 Bf[8];
  #pragma unroll
  for (int kk = 0; kk < 8; ++kk) {
    int kb = kh * 256 + kk * 32 + kq * 8;
    const float* p = whh + (size_t)grow * H_ + kb;
    float4 a = *reinterpret_cast<const float4*>(p);
    float4 b = *reinterpret_cast<const float4*>(p + 4);
    uint4 v;
    v.x = (unsigned)f2b(a.x) | ((unsigned)f2b(a.y) << 16);
    v.y = (unsigned)f2b(a.z) | ((unsigned)f2b(a.w) << 16);
    v.z = (unsigned)f2b(b.x) | ((unsigned)f2b(b.y) << 16);
    v.w = (unsigned)f2b(b.z) | ((unsigned)f2b(b.w) << 16);
    Bf[kk] = __builtin_bit_cast(bf16x8, v);
  }
  const float bhh_v = (kh == 0) ? b_hh[grow] : 0.0f;

  if (tid < 512) hown[tid] = 0.0f;
  const int i_e = (tid >> 5) & 15, c_e = tid & 31;
  const int lenv = len[g * 16 + i_e];
  int tmax = 0;
  for (int bi = 0; bi < 16; ++bi) {
    int l = len[g * 16 + bi];
    tmax = l > tmax ? l : tmax;
  }
  __syncthreads();

  int* fl = flags + g * 16 + (tid & 15);

  for (int t = 0; t < tmax; ++t) {
    // gi prefetch (independent of barrier -> issued early, arrives during spin)
    size_t gib = ((size_t)(t * 64 + wgid) * 16 + i_e) * 96;
    float i_r = b2f(gi[gib + c_e]);
    float i_z = b2f(gi[gib + 32 + c_e]);
    float i_n = b2f(gi[gib + 64 + c_e]);

    // wait until all 16 cluster WGs published h(t)
    if (tid < 64) {
      while (__hip_atomic_load(fl, __ATOMIC_RELAXED, __HIP_MEMORY_SCOPE_AGENT) < t) {}
    }
    __syncthreads();
    __threadfence();   // acquire: invalidate caches before reading h(t)

    // A-fragments of h(t) straight from L2 into frag layout, then MFMA chain
    const uint4* hx = reinterpret_cast<const uint4*>(
        xchg + ((size_t)((t & 1) * 4 + g) * 16) * H_);
    uint4 a[8];
    #pragma unroll
    for (int kk = 0; kk < 8; ++kk)
      a[kk] = hx[c16 * 64 + kh * 32 + kk * 4 + kq];
    f32x4 acc = f32x4{bhh_v, bhh_v, bhh_v, bhh_v};
    #pragma unroll
    for (int kk = 0; kk < 8; ++kk)
      acc = __builtin_amdgcn_mfma_f32_16x16x32_bf16(
          __builtin_bit_cast(bf16x8, a[kk]), Bf[kk], acc, 0, 0, 0);
    #pragma unroll
    for (int j = 0; j < 4; ++j)
      gh[kh][(kq * 4 + j) * 100 + nt * 16 + c16] = acc[j];
    __syncthreads();

    if (tid < 512) {
      float gr_ = gh[0][i_e * 100 + c_e]      + gh[1][i_e * 100 + c_e];
      float gz_ = gh[0][i_e * 100 + 32 + c_e] + gh[1][i_e * 100 + 32 + c_e];
      float gn_ = gh[0][i_e * 100 + 64 + c_e] + gh[1][i_e * 100 + 64 + c_e];
      float hp = hown[i_e * 32 + c_e];
      float r = 1.0f / (1.0f + __expf(-(i_r + gr_)));
      float z = 1.0f / (1.0f + __expf(-(i_z + gz_)));
      float pre = i_n + r * gn_;
      float e2 = __expf(2.0f * pre);
      float n = 1.0f - 2.0f / (e2 + 1.0f);
      float hn = z * (hp - n) + n;
      hown[i_e * 32 + c_e] = hn;
      xchg[((size_t)(((t + 1) & 1) * 4 + g) * 16 + i_e) * H_ + w * 32 + c_e] = f2b(hn);
      if (t + 1 == lenv) out[(size_t)(g * 16 + i_e) * H_ + w * 32 + c_e] = hn;
    }
    __threadfence();   // release: h(t+1) slice visible device-wide
    __syncthreads();
    if (tid == 0)
      __hip_atomic_store(flags + wgid, t + 1, __ATOMIC_RELEASE,
                         __HIP_MEMORY_SCOPE_AGENT);
  }
}

extern "C" void kernel_launch(void* const* d_in, const int* in_sizes, int n_in,
                              void* d_out, int out_size, void* d_ws, size_t ws_size,
                              hipStream_t stream) {
  const int*   x    = (const int*)d_in[0];
  const float* emb  = (const float*)d_in[1];
  const float* wih  = (const float*)d_in[2];
  const float* whh  = (const float*)d_in[3];
  const float* b_ih = (const float*)d_in[4];
  const float* b_hh = (const float*)d_in[5];
  float* out = (float*)d_out;

  char* ws = (char*)d_ws;
  const size_t GI_SZ    = (size_t)512 * 64 * 16 * 96 * 2;   // 100,663,296
  const size_t EMB_SZ   = (size_t)32000 * 256 * 2;          // 16,384,000
  const size_t WIH_SZ   = (size_t)1536 * 256 * 2;           //    786,432
  const size_t XCHG_SZ  = (size_t)2 * 4 * 16 * 512 * 2;     //    131,072
  const size_t FLAG_SZ  = 256;
  const size_t LEN_SZ   = 256;
  const size_t GI_OFF   = 0;
  const size_t EMB_OFF  = GI_OFF + GI_SZ;
  const size_t WIH_OFF  = EMB_OFF + EMB_SZ;
  const size_t XCHG_OFF = WIH_OFF + WIH_SZ;
  const size_t FLAG_OFF = XCHG_OFF + XCHG_SZ;
  const size_t LEN_OFF  = FLAG_OFF + FLAG_SZ;
  if (ws_size < LEN_OFF + LEN_SZ) return;   // need ~118 MB of scratch

  unsigned short* gi_p  = (unsigned short*)(ws + GI_OFF);
  unsigned short* emb_b = (unsigned short*)(ws + EMB_OFF);
  unsigned short* wih_b = (unsigned short*)(ws + WIH_OFF);
  unsigned short* xchg  = (unsigned short*)(ws + XCHG_OFF);
  int*            flags = (int*)(ws + FLAG_OFF);
  int*            len   = (int*)(ws + LEN_OFF);

  hipMemsetAsync(ws + XCHG_OFF, 0, XCHG_SZ + FLAG_SZ, stream);
  convert_kernel<<<2048, 256, 0, stream>>>(emb, wih, emb_b, wih_b);
  lengths_kernel<<<64, 512, 0, stream>>>(x, len);
  gi_kernel<<<dim3(64, 4, 16), 256, 0, stream>>>(x, emb_b, wih_b, b_ih, gi_p);
  scan_kernel<<<64, 768, 0, stream>>>(whh, b_hh, gi_p, len, xchg, flags, out);
}

// Round 4
// 3636.938 us; speedup vs baseline: 3.4744x; 3.4744x over previous
//
#include <hip/hip_runtime.h>
#include <stdint.h>

#define B_  64
#define S_  512
#define E_  256
#define H_  512

typedef float  f32x4  __attribute__((ext_vector_type(4)));
typedef __bf16 bf16x8 __attribute__((ext_vector_type(8)));

__device__ __forceinline__ unsigned short f2b(float f) {
  uint32_t u = __builtin_bit_cast(uint32_t, f);
  uint32_t r = (u + 0x7FFFu + ((u >> 16) & 1u)) >> 16;
  return (unsigned short)r;
}
__device__ __forceinline__ float b2f(unsigned short s) {
  uint32_t u = ((uint32_t)s) << 16;
  return __builtin_bit_cast(float, u);
}
__device__ __forceinline__ bf16x8 ld_bf8(const unsigned short* p) {
  uint4 v = *reinterpret_cast<const uint4*>(p);
  return __builtin_bit_cast(bf16x8, v);
}

// ---------------- convert emb + W_ih to bf16 ----------------
__global__ void convert_kernel(const float* __restrict__ emb,
                               const float* __restrict__ wih,
                               unsigned short* __restrict__ emb_b,
                               unsigned short* __restrict__ wih_b) {
  const int64_t EMB_N = (int64_t)32000 * 256;          // 8,192,000
  const int64_t TOT8  = (EMB_N + (int64_t)1536 * 256) / 8;
  for (int64_t i8 = (int64_t)blockIdx.x * blockDim.x + threadIdx.x; i8 < TOT8;
       i8 += (int64_t)gridDim.x * blockDim.x) {
    int64_t e = i8 * 8;
    const float* src; unsigned short* dst;
    if (e < EMB_N) { src = emb + e;           dst = emb_b + e; }
    else           { src = wih + (e - EMB_N); dst = wih_b + (e - EMB_N); }
    float4 a = *reinterpret_cast<const float4*>(src);
    float4 b = *reinterpret_cast<const float4*>(src + 4);
    uint4 o;
    o.x = (unsigned)f2b(a.x) | ((unsigned)f2b(a.y) << 16);
    o.y = (unsigned)f2b(a.z) | ((unsigned)f2b(a.w) << 16);
    o.z = (unsigned)f2b(b.x) | ((unsigned)f2b(b.y) << 16);
    o.w = (unsigned)f2b(b.z) | ((unsigned)f2b(b.w) << 16);
    *reinterpret_cast<uint4*>(dst) = o;
  }
}

// ---------------- sequence lengths ----------------
__global__ void lengths_kernel(const int* __restrict__ x, int* __restrict__ len) {
  __shared__ int part[8];
  int b = blockIdx.x, tid = threadIdx.x;
  int v = (x[b * S_ + tid] != 0) ? 1 : 0;
  unsigned long long m = __ballot(v);
  if ((tid & 63) == 0) part[tid >> 6] = __popcll(m);
  __syncthreads();
  if (tid == 0) {
    int s = 0;
    #pragma unroll
    for (int i = 0; i < 8; ++i) s += part[i];
    len[b] = s;
  }
}

// ---------------- phase 1: gi = emb[x] @ W_ih^T + b_ih  (permuted bf16 layout) ----
__global__ __launch_bounds__(256) void gi_kernel(
    const int* __restrict__ x, const unsigned short* __restrict__ emb_b,
    const unsigned short* __restrict__ wih_b, const float* __restrict__ b_ih,
    unsigned short* __restrict__ gi) {
  int tblk = blockIdx.x, g = blockIdx.y, w = blockIdx.z;
  int tid = threadIdx.x;
  int wv = tid >> 6, lane = tid & 63;
  int c16 = lane & 15, kq = lane >> 4;
  int t0 = tblk * 8 + wv, t1 = t0 + 4;

  int grow[6]; float bias[6];
  #pragma unroll
  for (int nt = 0; nt < 6; ++nt) {
    grow[nt] = (nt >> 1) * H_ + w * 32 + (nt & 1) * 16 + c16;
    bias[nt] = b_ih[grow[nt]];
  }
  int tok0 = x[(g * 16 + c16) * S_ + t0];
  int tok1 = x[(g * 16 + c16) * S_ + t1];

  f32x4 acc[2][6];
  #pragma unroll
  for (int nt = 0; nt < 6; ++nt) {
    acc[0][nt] = f32x4{bias[nt], bias[nt], bias[nt], bias[nt]};
    acc[1][nt] = acc[0][nt];
  }
  #pragma unroll
  for (int kk = 0; kk < 8; ++kk) {
    int kb = kk * 32 + kq * 8;
    bf16x8 A0 = ld_bf8(emb_b + (size_t)tok0 * E_ + kb);
    bf16x8 A1 = ld_bf8(emb_b + (size_t)tok1 * E_ + kb);
    #pragma unroll
    for (int nt = 0; nt < 6; ++nt) {
      bf16x8 Bf = ld_bf8(wih_b + (size_t)grow[nt] * E_ + kb);
      acc[0][nt] = __builtin_amdgcn_mfma_f32_16x16x32_bf16(A0, Bf, acc[0][nt], 0, 0, 0);
      acc[1][nt] = __builtin_amdgcn_mfma_f32_16x16x32_bf16(A1, Bf, acc[1][nt], 0, 0, 0);
    }
  }
  int wg = g * 16 + w;
  #pragma unroll
  for (int m = 0; m < 2; ++m) {
    int t = m ? t1 : t0;
    size_t base = ((size_t)(t * 64 + wg) * 16) * 96;
    #pragma unroll
    for (int nt = 0; nt < 6; ++nt)
      #pragma unroll
      for (int j = 0; j < 4; ++j)
        gi[base + (size_t)(kq * 4 + j) * 96 + nt * 16 + c16] = f2b(acc[m][nt][j]);
  }
}

// ---------------- phase 2: persistent GRU scan (fence-free protocol) ----------
// All cross-WG traffic (h exchange + flags) uses RELAXED SYSTEM-scope atomics
// -> global_load/store sc0 sc1: bypass L1 AND the non-coherent per-XCD L2,
// served at the coherence point. No threadfence (no buffer_wbl2/buffer_inv).
// Writer order: h stores -> s_waitcnt vmcnt(0) -> barrier -> flag store.
__global__ __launch_bounds__(768, 1) void scan_kernel(
    const float* __restrict__ whh, const float* __restrict__ b_hh,
    const unsigned short* __restrict__ gi, const int* __restrict__ len,
    unsigned short* __restrict__ xchg, int* __restrict__ flags,
    float* __restrict__ out) {
  __shared__ float gh[2][16 * 100];   // two K-halves, padded stride 100
  __shared__ float hown[16 * 32];     // own f32 slice of h

  const int wgid = blockIdx.x, g = wgid >> 4, w = wgid & 15;
  const int tid = threadIdx.x, wv = tid >> 6, lane = tid & 63;
  const int nt = wv % 6, kh = wv / 6;           // 12 waves: 6 n-tiles x 2 K-halves
  const int c16 = lane & 15, kq = lane >> 4;

  // loop-invariant W_hh B-fragments in registers (bf16)
  const int grow = (nt >> 1) * H_ + w * 32 + (nt & 1) * 16 + c16;
  bf16x8 Bf[8];
  #pragma unroll
  for (int kk = 0; kk < 8; ++kk) {
    int kb = kh * 256 + kk * 32 + kq * 8;
    const float* p = whh + (size_t)grow * H_ + kb;
    float4 a = *reinterpret_cast<const float4*>(p);
    float4 b = *reinterpret_cast<const float4*>(p + 4);
    uint4 v;
    v.x = (unsigned)f2b(a.x) | ((unsigned)f2b(a.y) << 16);
    v.y = (unsigned)f2b(a.z) | ((unsigned)f2b(a.w) << 16);
    v.z = (unsigned)f2b(b.x) | ((unsigned)f2b(b.y) << 16);
    v.w = (unsigned)f2b(b.z) | ((unsigned)f2b(b.w) << 16);
    Bf[kk] = __builtin_bit_cast(bf16x8, v);
  }
  const float bhh_v = (kh == 0) ? b_hh[grow] : 0.0f;

  if (tid < 512) hown[tid] = 0.0f;
  const int i_e = (tid >> 5) & 15, c_e = tid & 31;
  const int lenv = len[g * 16 + i_e];
  int tmax = 0;
  for (int bi = 0; bi < 16; ++bi) {
    int l = len[g * 16 + bi];
    tmax = l > tmax ? l : tmax;
  }
  __syncthreads();

  int* fl = flags + (g * 16 + (tid & 15)) * 16;   // flags padded to 64B

  for (int t = 0; t < tmax; ++t) {
    // gi prefetch (independent of handshake -> issued early)
    size_t gib = ((size_t)(t * 64 + wgid) * 16 + i_e) * 96;
    float i_r = b2f(gi[gib + c_e]);
    float i_z = b2f(gi[gib + 32 + c_e]);
    float i_n = b2f(gi[gib + 64 + c_e]);

    // wait until all 16 cluster WGs published h(t) — coherent poll, no fence.
    // one lane per peer flag (16 pollers) to minimize IC line contention.
    if (tid < 16) {
      while (__hip_atomic_load(fl, __ATOMIC_RELAXED,
                               __HIP_MEMORY_SCOPE_SYSTEM) < t) {}
    }
    __syncthreads();

    // A-fragments of h(t): coherent 8B loads from the exchange buffer
    const unsigned long long* hx8 = reinterpret_cast<const unsigned long long*>(
        xchg + ((size_t)((t & 1) * 4 + g) * 16) * H_);
    uint4 a[8];
    #pragma unroll
    for (int kk = 0; kk < 8; ++kk) {
      int u64i = (c16 * 64 + kh * 32 + kk * 4 + kq) * 2;
      unsigned long long lo = __hip_atomic_load(hx8 + u64i, __ATOMIC_RELAXED,
                                                __HIP_MEMORY_SCOPE_SYSTEM);
      unsigned long long hi = __hip_atomic_load(hx8 + u64i + 1, __ATOMIC_RELAXED,
                                                __HIP_MEMORY_SCOPE_SYSTEM);
      a[kk].x = (unsigned)lo; a[kk].y = (unsigned)(lo >> 32);
      a[kk].z = (unsigned)hi; a[kk].w = (unsigned)(hi >> 32);
    }
    f32x4 acc = f32x4{bhh_v, bhh_v, bhh_v, bhh_v};
    #pragma unroll
    for (int kk = 0; kk < 8; ++kk)
      acc = __builtin_amdgcn_mfma_f32_16x16x32_bf16(
          __builtin_bit_cast(bf16x8, a[kk]), Bf[kk], acc, 0, 0, 0);
    #pragma unroll
    for (int j = 0; j < 4; ++j)
      gh[kh][(kq * 4 + j) * 100 + nt * 16 + c16] = acc[j];
    __syncthreads();

    if (tid < 512) {
      float gr_ = gh[0][i_e * 100 + c_e]      + gh[1][i_e * 100 + c_e];
      float gz_ = gh[0][i_e * 100 + 32 + c_e] + gh[1][i_e * 100 + 32 + c_e];
      float gn_ = gh[0][i_e * 100 + 64 + c_e] + gh[1][i_e * 100 + 64 + c_e];
      float hp = hown[i_e * 32 + c_e];
      float r = 1.0f / (1.0f + __expf(-(i_r + gr_)));
      float z = 1.0f / (1.0f + __expf(-(i_z + gz_)));
      float pre = i_n + r * gn_;
      float e2 = __expf(2.0f * pre);
      float n = 1.0f - 2.0f / (e2 + 1.0f);
      float hn = z * (hp - n) + n;
      hown[i_e * 32 + c_e] = hn;
      // pack 2 bf16 per lane-pair, coherent write-through store
      unsigned short hb = f2b(hn);
      unsigned nb = (unsigned)__shfl_down((int)hb, 1) & 0xFFFFu;
      if ((c_e & 1) == 0) {
        uint32_t pack = (uint32_t)hb | (nb << 16);
        uint32_t* dst = reinterpret_cast<uint32_t*>(
            xchg + ((size_t)(((t + 1) & 1) * 4 + g) * 16 + i_e) * H_ +
            w * 32 + c_e);
        __hip_atomic_store(dst, pack, __ATOMIC_RELAXED,
                           __HIP_MEMORY_SCOPE_SYSTEM);
      }
      if (t + 1 == lenv) out[(size_t)(g * 16 + i_e) * H_ + w * 32 + c_e] = hn;
    }
    // writer-side ordering: drain write-through stores, then publish flag
    asm volatile("s_waitcnt vmcnt(0)" ::: "memory");
    __syncthreads();
    if (tid == 0)
      __hip_atomic_store(flags + wgid * 16, t + 1, __ATOMIC_RELAXED,
                         __HIP_MEMORY_SCOPE_SYSTEM);
  }
}

extern "C" void kernel_launch(void* const* d_in, const int* in_sizes, int n_in,
                              void* d_out, int out_size, void* d_ws, size_t ws_size,
                              hipStream_t stream) {
  const int*   x    = (const int*)d_in[0];
  const float* emb  = (const float*)d_in[1];
  const float* wih  = (const float*)d_in[2];
  const float* whh  = (const float*)d_in[3];
  const float* b_ih = (const float*)d_in[4];
  const float* b_hh = (const float*)d_in[5];
  float* out = (float*)d_out;

  char* ws = (char*)d_ws;
  const size_t GI_SZ    = (size_t)512 * 64 * 16 * 96 * 2;   // 100,663,296
  const size_t EMB_SZ   = (size_t)32000 * 256 * 2;          // 16,384,000
  const size_t WIH_SZ   = (size_t)1536 * 256 * 2;           //    786,432
  const size_t XCHG_SZ  = (size_t)2 * 4 * 16 * 512 * 2;     //    131,072
  const size_t FLAG_SZ  = 64 * 64;                          // 64B-padded flags
  const size_t LEN_SZ   = 256;
  const size_t GI_OFF   = 0;
  const size_t EMB_OFF  = GI_OFF + GI_SZ;
  const size_t WIH_OFF  = EMB_OFF + EMB_SZ;
  const size_t XCHG_OFF = WIH_OFF + WIH_SZ;
  const size_t FLAG_OFF = XCHG_OFF + XCHG_SZ;
  const size_t LEN_OFF  = FLAG_OFF + FLAG_SZ;
  if (ws_size < LEN_OFF + LEN_SZ) return;   // need ~118 MB of scratch

  unsigned short* gi_p  = (unsigned short*)(ws + GI_OFF);
  unsigned short* emb_b = (unsigned short*)(ws + EMB_OFF);
  unsigned short* wih_b = (unsigned short*)(ws + WIH_OFF);
  unsigned short* xchg  = (unsigned short*)(ws + XCHG_OFF);
  int*            flags = (int*)(ws + FLAG_OFF);
  int*            len   = (int*)(ws + LEN_OFF);

  hipMemsetAsync(ws + XCHG_OFF, 0, XCHG_SZ + FLAG_SZ, stream);
  convert_kernel<<<2048, 256, 0, stream>>>(emb, wih, emb_b, wih_b);
  lengths_kernel<<<64, 512, 0, stream>>>(x, len);
  gi_kernel<<<dim3(64, 4, 16), 256, 0, stream>>>(x, emb_b, wih_b, b_ih, gi_p);
  scan_kernel<<<64, 768, 0, stream>>>(whh, b_hh, gi_p, len, xchg, flags, out);
}